// Round 3
// baseline (561.279 us; speedup 1.0000x reference)
//
#include <hip/hip_runtime.h>
#include <hip/hip_bf16.h>

// Problem constants (setup_inputs fixed: B=16, z_dim=64, H=W=32, M=4096)
#define ZD    64
#define MM    4096
#define NN    16384
#define HWSZ  1024
#define BB    16
#define NPART 128      // NN / 128 = number of n-block partials per column

typedef __bf16 bf16x8 __attribute__((ext_vector_type(8)));
typedef float  f32x4  __attribute__((ext_vector_type(4)));

#define EMA_C 0.999f
#define EPS_C 1e-8f

// ---------------------------------------------------------------------------
// k_prep (merged): blocks [0,256): z transpose->bf16 + zn2
//                  blocks [256,1280): e->bf16 + en2 + sume init
// ---------------------------------------------------------------------------
__global__ __launch_bounds__(256) void k_prep(const float* __restrict__ z,
                                              const float* __restrict__ e,
                                              __hip_bfloat16* __restrict__ zf,
                                              __hip_bfloat16* __restrict__ ebf,
                                              float* __restrict__ zn2,
                                              float* __restrict__ en2,
                                              float* __restrict__ sume) {
    __shared__ float tile[64][65];
    __shared__ float part[4][64];
    int blk = blockIdx.x;
    int tid = threadIdx.x;
    if (blk < 256) {
        // ---- z prep: b = blk>>4, hw-tile = blk&15 ----
        int b   = blk >> 4;
        int hw0 = (blk & 15) * 64;
        int tx = tid & 63, ty = tid >> 6;
        const float* zp = z + (size_t)b * (ZD * HWSZ);
#pragma unroll
        for (int kk = 0; kk < 16; kk++) {
            int k = kk * 4 + ty;
            tile[k][tx] = zp[(size_t)k * HWSZ + hw0 + tx];  // coalesced
        }
        __syncthreads();
#pragma unroll
        for (int i = 0; i < 16; i++) {   // coalesced bf16 row writes
            int li = tid + i * 256;
            int ln = li >> 6, lk = li & 63;
            int n = b * HWSZ + hw0 + ln;
            zf[(size_t)n * ZD + lk] = __float2bfloat16(tile[lk][ln]);
        }
        float s = 0.f;
#pragma unroll
        for (int kk = 0; kk < 16; kk++) {
            float q = __bfloat162float(__float2bfloat16(tile[ty + kk * 4][tx]));
            s += q * q;
        }
        part[ty][tx] = s;
        __syncthreads();
        if (tid < 64) {
            float t = part[0][tid] + part[1][tid] + part[2][tid] + part[3][tid];
            zn2[b * HWSZ + hw0 + tid] = t;
        }
    } else {
        // ---- e prep + sume init ----
        int eb  = blk - 256;            // 0..1023
        int gid = eb * 256 + tid;
        if (gid < MM) sume[gid] = 0.f;  // ws poisoned 0xAA each launch
        int wave = tid >> 6, lane = tid & 63;
        int row = eb * 4 + wave;
        if (row < MM) {
            float v = e[row * ZD + lane];
            __hip_bfloat16 b16 = __float2bfloat16(v);
            ebf[row * ZD + lane] = b16;
            float q = __bfloat162float(b16);  // norm from quantized value
            float s = q * q;
            for (int off = 32; off; off >>= 1) s += __shfl_xor(s, off);
            if (lane == 0) en2[row] = s;
        }
    }
}

// ---------------------------------------------------------------------------
// k_pass1: A = ebf rows (m), B = zf rows (n) so D: row = m = lq*4+reg
// (4 consecutive m per lane), col = n = l16. belong is read with per-lane
// float4 nontemporal loads (one wave instr = 16 full 64B lines).
// Reductions in SQUARED domain (no per-element sqrt):
//   pmax[y][m] = max_n belong^2 * d2   (belong>=0, sqrt is monotone)
//   pmin[y][m] = min_n d2              (clamped at consume time)
// Per-block results go to contention-free coalesced partial stores.
// ---------------------------------------------------------------------------
__global__ __launch_bounds__(256) void k_pass1(const __hip_bfloat16* __restrict__ zf,
                                               const __hip_bfloat16* __restrict__ ebf,
                                               const float* __restrict__ zn2,
                                               const float* __restrict__ en2,
                                               const float* __restrict__ belong,
                                               float* __restrict__ pmax,
                                               float* __restrict__ pmin) {
    int tid = threadIdx.x;
    int wave = tid >> 6, lane = tid & 63;
    int l16 = lane & 15, lq = lane >> 4;
    int wm = wave & 1, wn = wave >> 1;
    int m0 = blockIdx.x * 64 + wm * 32;
    int n0 = blockIdx.y * 128 + wn * 64;

    const bf16x8* ebv = reinterpret_cast<const bf16x8*>(ebf);
    const bf16x8* zfv = reinterpret_cast<const bf16x8*>(zf);

    bf16x8 Af[2][2], Bf[4][2];
#pragma unroll
    for (int im = 0; im < 2; im++)
#pragma unroll
        for (int h = 0; h < 2; h++)
            Af[im][h] = ebv[(size_t)(m0 + im * 16 + l16) * 8 + h * 4 + lq];
#pragma unroll
    for (int jn = 0; jn < 4; jn++)
#pragma unroll
        for (int h = 0; h < 2; h++)
            Bf[jn][h] = zfv[(size_t)(n0 + jn * 16 + l16) * 8 + h * 4 + lq];

    // belong: float4 per (im, jn), nontemporal (read-once stream)
    f32x4 bl[2][4];
#pragma unroll
    for (int im = 0; im < 2; im++)
#pragma unroll
        for (int jn = 0; jn < 4; jn++) {
            const f32x4* bp = reinterpret_cast<const f32x4*>(
                belong + (size_t)(n0 + jn * 16 + l16) * MM + (m0 + im * 16 + lq * 4));
            bl[im][jn] = __builtin_nontemporal_load(bp);
        }

    f32x4 acc[2][4];
#pragma unroll
    for (int im = 0; im < 2; im++)
#pragma unroll
        for (int jn = 0; jn < 4; jn++) {
            acc[im][jn] = (f32x4){0.f, 0.f, 0.f, 0.f};
            acc[im][jn] = __builtin_amdgcn_mfma_f32_16x16x32_bf16(Af[im][0], Bf[jn][0], acc[im][jn], 0, 0, 0);
            acc[im][jn] = __builtin_amdgcn_mfma_f32_16x16x32_bf16(Af[im][1], Bf[jn][1], acc[im][jn], 0, 0, 0);
        }

    f32x4 en2v[2];
#pragma unroll
    for (int im = 0; im < 2; im++)
        en2v[im] = *reinterpret_cast<const f32x4*>(en2 + m0 + im * 16 + lq * 4);
    float zn2v[4];
#pragma unroll
    for (int jn = 0; jn < 4; jn++)
        zn2v[jn] = zn2[n0 + jn * 16 + l16];

    float vmax[2][4], vmin[2][4];
#pragma unroll
    for (int im = 0; im < 2; im++)
#pragma unroll
        for (int r = 0; r < 4; r++) { vmax[im][r] = 0.f; vmin[im][r] = 3.4e38f; }

#pragma unroll
    for (int im = 0; im < 2; im++)
#pragma unroll
        for (int jn = 0; jn < 4; jn++)
#pragma unroll
            for (int r = 0; r < 4; r++) {
                float d2  = fmaf(-2.f, acc[im][jn][r], en2v[im][r] + zn2v[jn]);
                float bel = bl[im][jn][r];
                vmax[im][r] = fmaxf(vmax[im][r], bel * bel * d2);
                vmin[im][r] = fminf(vmin[im][r], d2);
            }

    // reduce across the 16 l16 lanes (n direction) within each quad
#pragma unroll
    for (int off = 1; off < 16; off <<= 1)
#pragma unroll
        for (int im = 0; im < 2; im++)
#pragma unroll
            for (int r = 0; r < 4; r++) {
                vmax[im][r] = fmaxf(vmax[im][r], __shfl_xor(vmax[im][r], off));
                vmin[im][r] = fminf(vmin[im][r], __shfl_xor(vmin[im][r], off));
            }

    // merge the two n-halves (wn) via LDS; values >= 0 so uint compare works
    // for max; min may see tiny negatives -> bias by flipping sign path: use
    // int compare trick only for max, and float atomic-free two-slot min:
    __shared__ unsigned smax[64];
    __shared__ float    smin2[2][64];
    if (tid < 64) smax[tid] = 0u;
    __syncthreads();
    if (l16 == 0) {
#pragma unroll
        for (int im = 0; im < 2; im++)
#pragma unroll
            for (int r = 0; r < 4; r++) {
                int ml = wm * 32 + im * 16 + lq * 4 + r;
                atomicMax(&smax[ml], __float_as_uint(fmaxf(vmax[im][r], 0.f)));
                smin2[wn][ml] = vmin[im][r];   // distinct slot per n-half
            }
    }
    __syncthreads();
    if (tid < 64) {
        int m = blockIdx.x * 64 + tid;
        pmax[(size_t)blockIdx.y * MM + m] = __uint_as_float(smax[tid]);
        pmin[(size_t)blockIdx.y * MM + m] = fminf(smin2[0][tid], smin2[1][tid]);
    }
}

// ---------------------------------------------------------------------------
// k_pass2: prologue reduces the NPART partials per column -> nm^2, ref
// (deterministic sequential loop => bit-identical across blocks; block x==0
// materializes refs). Main loop recomputes d^2 (D col = m orientation),
// applies the threshold transform sqrt-free on the hot path, accumulates
// sum_exp[m] += exp(alpha*t - ref).
// ---------------------------------------------------------------------------
__global__ __launch_bounds__(256) void k_pass2(const __hip_bfloat16* __restrict__ zf,
                                               const __hip_bfloat16* __restrict__ ebf,
                                               const float* __restrict__ zn2,
                                               const float* __restrict__ en2,
                                               const float* __restrict__ pmax,
                                               const float* __restrict__ pmin,
                                               const float* __restrict__ max_distance,
                                               const float* __restrict__ log_sigma,
                                               const int* __restrict__ pp,
                                               float* __restrict__ refs,
                                               float* __restrict__ sume) {
    __shared__ float sred[256];
    __shared__ float snm2[128], sref[128], ssum[128];
    int tid = threadIdx.x;

    int p = pp[0];
    float alpha = -0.5f * __expf(-2.f * log_sigma[0]);

    // ---- prologue: reduce partials for this block's 128 columns ----
    {
        int half = tid >> 7;               // 0: max-reduce pmax, 1: min pmin
        int col  = tid & 127;
        int m    = blockIdx.y * 128 + col;
        const float* base = (half ? pmin : pmax) + m;
        float a0 = half ? 3.4e38f : 0.f;
#pragma unroll 8
        for (int yp = 0; yp < NPART; yp++) {
            float v = base[(size_t)yp * MM];
            a0 = half ? fminf(a0, v) : fmaxf(a0, v);   // wave-uniform select
        }
        sred[tid] = a0;
    }
    __syncthreads();
    if (tid < 128) {
        int m = blockIdx.y * 128 + tid;
        float bm = sqrtf(fmaxf(sred[tid], 0.f));        // batch max belong*d
        float dm = sqrtf(fmaxf(sred[tid + 128], 0.f));  // min d
        float nm = fmaxf(EMA_C * max_distance[m] + (1.f - EMA_C) * bm, EPS_C);
        float tlow;
        if (p == 2) {
            float d4  = (dm * dm) * (dm * dm);
            float nm4 = (nm * nm) * (nm * nm);
            tlow = (dm < nm) ? fminf(dm, nm4) : d4;
        } else {
            float e1 = 2.f / (float)p, e2 = 2.f * (float)p;
            tlow = (dm < nm) ? fminf(powf(dm, e1), powf(nm, e2)) : powf(dm, e2);
        }
        float rf = alpha * tlow;   // alpha<0, t>=tlow => s<=rf (no overflow)
        snm2[tid] = nm * nm;
        sref[tid] = rf;
        ssum[tid] = 0.f;
        if (blockIdx.x == 0) refs[m] = rf;
    }
    __syncthreads();

    int wave = tid >> 6, lane = tid & 63;
    int l16 = lane & 15, lq = lane >> 4;
    int wn = wave >> 1, wm = wave & 1;
    int n0 = blockIdx.x * 64 + wn * 32;
    int m0 = blockIdx.y * 128 + wm * 64;

    const bf16x8* zfv = reinterpret_cast<const bf16x8*>(zf);
    const bf16x8* ebv = reinterpret_cast<const bf16x8*>(ebf);

    bf16x8 Af[2][2], Bf[4][2];
#pragma unroll
    for (int i = 0; i < 2; i++)
#pragma unroll
        for (int h = 0; h < 2; h++)
            Af[i][h] = zfv[(size_t)(n0 + i * 16 + l16) * 8 + h * 4 + lq];
#pragma unroll
    for (int j = 0; j < 4; j++)
#pragma unroll
        for (int h = 0; h < 2; h++)
            Bf[j][h] = ebv[(size_t)(m0 + j * 16 + l16) * 8 + h * 4 + lq];

    f32x4 acc[2][4];
#pragma unroll
    for (int i = 0; i < 2; i++)
#pragma unroll
        for (int j = 0; j < 4; j++) {
            acc[i][j] = (f32x4){0.f, 0.f, 0.f, 0.f};
            acc[i][j] = __builtin_amdgcn_mfma_f32_16x16x32_bf16(Af[i][0], Bf[j][0], acc[i][j], 0, 0, 0);
            acc[i][j] = __builtin_amdgcn_mfma_f32_16x16x32_bf16(Af[i][1], Bf[j][1], acc[i][j], 0, 0, 0);
        }

    f32x4 zn2v[2];
#pragma unroll
    for (int i = 0; i < 2; i++)
        zn2v[i] = *reinterpret_cast<const f32x4*>(zn2 + n0 + i * 16 + lq * 4);

    bool p2 = (p == 2);
    float pe = (float)p, pi = 1.f / (float)p;

#pragma unroll
    for (int j = 0; j < 4; j++) {
        float en2v = en2[m0 + j * 16 + l16];
        float nm2v = snm2[wm * 64 + j * 16 + l16];
        float rfv  = sref[wm * 64 + j * 16 + l16];
        float csum = 0.f;
#pragma unroll
        for (int i = 0; i < 2; i++)
#pragma unroll
            for (int r = 0; r < 4; r++) {
                float d2c = fmaxf(zn2v[i][r] + en2v - 2.f * acc[i][j][r], 0.f);
                float t;
                if (p2) {
                    t = d2c * d2c;                       // hot: d^4
                    if (__any(d2c < nm2v))               // rare, wave-uniform
                        t = (d2c < nm2v) ? sqrtf(d2c) : t;
                } else {
                    t = powf(d2c, (d2c < nm2v) ? pi : pe);
                }
                csum += __expf(fmaf(alpha, t, -rfv));
            }
        csum += __shfl_xor(csum, 16);
        csum += __shfl_xor(csum, 32);
        if (lane < 16) atomicAdd(&ssum[wm * 64 + j * 16 + lane], csum);
    }
    __syncthreads();
    if (tid < 128) atomicAdd(&sume[blockIdx.y * 128 + tid], ssum[tid]);
}

// ---------------------------------------------------------------------------
// k_final: loss = -mean(ref + log(sum_exp)) + z_dim * log_sigma
// ---------------------------------------------------------------------------
__global__ __launch_bounds__(256) void k_final(const float* __restrict__ refs,
                                               const float* __restrict__ sume,
                                               const float* __restrict__ log_sigma,
                                               float* __restrict__ out) {
    __shared__ float red[4];
    int tid = threadIdx.x;
    float a = 0.f;
    for (int m = tid; m < MM; m += 256)
        a += refs[m] + logf(fmaxf(sume[m], 1e-30f));
    for (int off = 32; off; off >>= 1) a += __shfl_xor(a, off);
    int wave = tid >> 6, lane = tid & 63;
    if (lane == 0) red[wave] = a;
    __syncthreads();
    if (tid == 0) {
        float t = red[0] + red[1] + red[2] + red[3];
        out[0] = -t / (float)MM + (float)ZD * log_sigma[0];
    }
}

// ---------------------------------------------------------------------------
extern "C" void kernel_launch(void* const* d_in, const int* in_sizes, int n_in,
                              void* d_out, int out_size, void* d_ws, size_t ws_size,
                              hipStream_t stream) {
    const float* z            = (const float*)d_in[0];
    const float* e            = (const float*)d_in[1];
    const float* belong       = (const float*)d_in[2];
    const float* log_sigma    = (const float*)d_in[3];
    const float* max_distance = (const float*)d_in[4];
    const int*   pp           = (const int*)d_in[5];
    float* out = (float*)d_out;

    char* ws = (char*)d_ws;
    __hip_bfloat16* zf  = (__hip_bfloat16*)(ws + 0);        // 2,097,152 B
    __hip_bfloat16* ebf = (__hip_bfloat16*)(ws + 2097152);  //   524,288 B
    float* zn2  = (float*)(ws + 2621440);                   //    65,536 B
    float* en2  = (float*)(ws + 2686976);                   //    16,384 B
    float* pmax = (float*)(ws + 2703360);                   // 2,097,152 B
    float* pmin = (float*)(ws + 4800512);                   // 2,097,152 B
    float* refs = (float*)(ws + 6897664);                   //    16,384 B
    float* sume = (float*)(ws + 6914048);                   //    16,384 B

    k_prep<<<1280, 256, 0, stream>>>(z, e, zf, ebf, zn2, en2, sume);
    k_pass1<<<dim3(MM / 64, NN / 128), 256, 0, stream>>>(zf, ebf, zn2, en2, belong, pmax, pmin);
    k_pass2<<<dim3(NN / 64, MM / 128), 256, 0, stream>>>(zf, ebf, zn2, en2, pmax, pmin,
                                                         max_distance, log_sigma, pp, refs, sume);
    k_final<<<1, 256, 0, stream>>>(refs, sume, log_sigma, out);
}

// Round 6
// 494.672 us; speedup vs baseline: 1.1346x; 1.1346x over previous
//
#include <hip/hip_runtime.h>
#include <hip/hip_bf16.h>

// Problem constants (setup_inputs fixed: B=16, z_dim=64, H=W=32, M=4096)
#define ZD    64
#define MM    4096
#define NN    16384
#define HWSZ  1024
#define BB    16
#define NPART 128      // NN / 128 = number of n-block partials per column

typedef __bf16 bf16x8 __attribute__((ext_vector_type(8)));
typedef float  f32x4  __attribute__((ext_vector_type(4)));

#define EMA_C 0.999f
#define EPS_C 1e-8f

// ---------------------------------------------------------------------------
// k_prep (merged): blocks [0,256): z transpose->bf16 + zn2
//                  blocks [256,1280): e->bf16 + en2 + sume init
// ---------------------------------------------------------------------------
__global__ __launch_bounds__(256) void k_prep(const float* __restrict__ z,
                                              const float* __restrict__ e,
                                              __hip_bfloat16* __restrict__ zf,
                                              __hip_bfloat16* __restrict__ ebf,
                                              float* __restrict__ zn2,
                                              float* __restrict__ en2,
                                              float* __restrict__ sume) {
    __shared__ float tile[64][65];
    __shared__ float part[4][64];
    int blk = blockIdx.x;
    int tid = threadIdx.x;
    if (blk < 256) {
        // ---- z prep: b = blk>>4, hw-tile = blk&15 ----
        int b   = blk >> 4;
        int hw0 = (blk & 15) * 64;
        int tx = tid & 63, ty = tid >> 6;
        const float* zp = z + (size_t)b * (ZD * HWSZ);
#pragma unroll
        for (int kk = 0; kk < 16; kk++) {
            int k = kk * 4 + ty;
            tile[k][tx] = zp[(size_t)k * HWSZ + hw0 + tx];  // coalesced
        }
        __syncthreads();
#pragma unroll
        for (int i = 0; i < 16; i++) {   // coalesced bf16 row writes
            int li = tid + i * 256;
            int ln = li >> 6, lk = li & 63;
            int n = b * HWSZ + hw0 + ln;
            zf[(size_t)n * ZD + lk] = __float2bfloat16(tile[lk][ln]);
        }
        float s = 0.f;
#pragma unroll
        for (int kk = 0; kk < 16; kk++) {
            float q = __bfloat162float(__float2bfloat16(tile[ty + kk * 4][tx]));
            s += q * q;
        }
        part[ty][tx] = s;
        __syncthreads();
        if (tid < 64) {
            float t = part[0][tid] + part[1][tid] + part[2][tid] + part[3][tid];
            zn2[b * HWSZ + hw0 + tid] = t;
        }
    } else {
        // ---- e prep + sume init ----
        int eb  = blk - 256;            // 0..1023
        int gid = eb * 256 + tid;
        if (gid < MM) sume[gid] = 0.f;  // ws poisoned 0xAA each launch
        int wave = tid >> 6, lane = tid & 63;
        int row = eb * 4 + wave;
        if (row < MM) {
            float v = e[row * ZD + lane];
            __hip_bfloat16 b16 = __float2bfloat16(v);
            ebf[row * ZD + lane] = b16;
            float q = __bfloat162float(b16);  // norm from quantized value
            float s = q * q;
            for (int off = 32; off; off >>= 1) s += __shfl_xor(s, off);
            if (lane == 0) en2[row] = s;
        }
    }
}

// ---------------------------------------------------------------------------
// k_pass1: A = ebf rows (m), B = zf rows (n) so D: row = m = lq*4+reg
// (4 consecutive m per lane), col = n = l16. belong read with per-lane
// float4 nontemporal loads (one wave instr = 16 full 64B lines = 1 KiB).
// Reductions in SQUARED domain (no per-element sqrt):
//   pmax[y][m] = max_n belong^2 * d2 ; pmin[y][m] = min_n d2
// Contention-free coalesced partial stores (no global atomics).
// ---------------------------------------------------------------------------
__global__ __launch_bounds__(256) void k_pass1(const __hip_bfloat16* __restrict__ zf,
                                               const __hip_bfloat16* __restrict__ ebf,
                                               const float* __restrict__ zn2,
                                               const float* __restrict__ en2,
                                               const float* __restrict__ belong,
                                               float* __restrict__ pmax,
                                               float* __restrict__ pmin) {
    int tid = threadIdx.x;
    int wave = tid >> 6, lane = tid & 63;
    int l16 = lane & 15, lq = lane >> 4;
    int wm = wave & 1, wn = wave >> 1;
    int m0 = blockIdx.x * 64 + wm * 32;
    int n0 = blockIdx.y * 128 + wn * 64;

    const bf16x8* ebv = reinterpret_cast<const bf16x8*>(ebf);
    const bf16x8* zfv = reinterpret_cast<const bf16x8*>(zf);

    bf16x8 Af[2][2], Bf[4][2];
#pragma unroll
    for (int im = 0; im < 2; im++)
#pragma unroll
        for (int h = 0; h < 2; h++)
            Af[im][h] = ebv[(size_t)(m0 + im * 16 + l16) * 8 + h * 4 + lq];
#pragma unroll
    for (int jn = 0; jn < 4; jn++)
#pragma unroll
        for (int h = 0; h < 2; h++)
            Bf[jn][h] = zfv[(size_t)(n0 + jn * 16 + l16) * 8 + h * 4 + lq];

    f32x4 bl[2][4];
#pragma unroll
    for (int im = 0; im < 2; im++)
#pragma unroll
        for (int jn = 0; jn < 4; jn++) {
            const f32x4* bp = reinterpret_cast<const f32x4*>(
                belong + (size_t)(n0 + jn * 16 + l16) * MM + (m0 + im * 16 + lq * 4));
            bl[im][jn] = __builtin_nontemporal_load(bp);
        }

    f32x4 acc[2][4];
#pragma unroll
    for (int im = 0; im < 2; im++)
#pragma unroll
        for (int jn = 0; jn < 4; jn++) {
            acc[im][jn] = (f32x4){0.f, 0.f, 0.f, 0.f};
            acc[im][jn] = __builtin_amdgcn_mfma_f32_16x16x32_bf16(Af[im][0], Bf[jn][0], acc[im][jn], 0, 0, 0);
            acc[im][jn] = __builtin_amdgcn_mfma_f32_16x16x32_bf16(Af[im][1], Bf[jn][1], acc[im][jn], 0, 0, 0);
        }

    f32x4 en2v[2];
#pragma unroll
    for (int im = 0; im < 2; im++)
        en2v[im] = *reinterpret_cast<const f32x4*>(en2 + m0 + im * 16 + lq * 4);
    float zn2v[4];
#pragma unroll
    for (int jn = 0; jn < 4; jn++)
        zn2v[jn] = zn2[n0 + jn * 16 + l16];

    float vmax[2][4], vmin[2][4];
#pragma unroll
    for (int im = 0; im < 2; im++)
#pragma unroll
        for (int r = 0; r < 4; r++) { vmax[im][r] = 0.f; vmin[im][r] = 3.4e38f; }

#pragma unroll
    for (int im = 0; im < 2; im++)
#pragma unroll
        for (int jn = 0; jn < 4; jn++)
#pragma unroll
            for (int r = 0; r < 4; r++) {
                float d2  = fmaf(-2.f, acc[im][jn][r], en2v[im][r] + zn2v[jn]);
                float bel = bl[im][jn][r];
                vmax[im][r] = fmaxf(vmax[im][r], bel * bel * d2);
                vmin[im][r] = fminf(vmin[im][r], d2);
            }

    // reduce across the 16 l16 lanes (n direction)
#pragma unroll
    for (int off = 1; off < 16; off <<= 1)
#pragma unroll
        for (int im = 0; im < 2; im++)
#pragma unroll
            for (int r = 0; r < 4; r++) {
                vmax[im][r] = fmaxf(vmax[im][r], __shfl_xor(vmax[im][r], off));
                vmin[im][r] = fminf(vmin[im][r], __shfl_xor(vmin[im][r], off));
            }

    __shared__ unsigned smax[64];
    __shared__ float    smin2[2][64];
    if (tid < 64) smax[tid] = 0u;
    __syncthreads();
    if (l16 == 0) {
#pragma unroll
        for (int im = 0; im < 2; im++)
#pragma unroll
            for (int r = 0; r < 4; r++) {
                int ml = wm * 32 + im * 16 + lq * 4 + r;
                atomicMax(&smax[ml], __float_as_uint(fmaxf(vmax[im][r], 0.f)));
                smin2[wn][ml] = vmin[im][r];   // distinct slot per n-half
            }
    }
    __syncthreads();
    if (tid < 64) {
        int m = blockIdx.x * 64 + tid;
        pmax[(size_t)blockIdx.y * MM + m] = __uint_as_float(smax[tid]);
        pmin[(size_t)blockIdx.y * MM + m] = fminf(smin2[0][tid], smin2[1][tid]);
    }
}

// ---------------------------------------------------------------------------
// k_mid: reduce the NPART partials per column ONCE -> nm2[m], refs[m].
// 64 blocks; block handles 64 columns; 4 thread-groups split the partials.
// ---------------------------------------------------------------------------
__global__ __launch_bounds__(256) void k_mid(const float* __restrict__ pmax,
                                             const float* __restrict__ pmin,
                                             const float* __restrict__ max_distance,
                                             const float* __restrict__ log_sigma,
                                             const int* __restrict__ pp,
                                             float* __restrict__ nm2,
                                             float* __restrict__ refs) {
    __shared__ float sx[4][64], sn[4][64];
    int tid = threadIdx.x;
    int col = tid & 63, grp = tid >> 6;
    int m = blockIdx.x * 64 + col;
    float vmax = 0.f, vmin = 3.4e38f;
#pragma unroll 8
    for (int yp = grp * (NPART / 4); yp < (grp + 1) * (NPART / 4); yp++) {
        vmax = fmaxf(vmax, pmax[(size_t)yp * MM + m]);   // coalesced per wave
        vmin = fminf(vmin, pmin[(size_t)yp * MM + m]);
    }
    sx[grp][col] = vmax;
    sn[grp][col] = vmin;
    __syncthreads();
    if (tid < 64) {
        float bx = fmaxf(fmaxf(sx[0][tid], sx[1][tid]), fmaxf(sx[2][tid], sx[3][tid]));
        float dn = fminf(fminf(sn[0][tid], sn[1][tid]), fminf(sn[2][tid], sn[3][tid]));
        int mm = blockIdx.x * 64 + tid;
        float bm = sqrtf(fmaxf(bx, 0.f));   // batch max belong*d
        float dm = sqrtf(fmaxf(dn, 0.f));   // min d over n
        float nm = fmaxf(EMA_C * max_distance[mm] + (1.f - EMA_C) * bm, EPS_C);
        int p = pp[0];
        float tlow;
        if (p == 2) {
            float d4  = (dm * dm) * (dm * dm);
            float nm4 = (nm * nm) * (nm * nm);
            tlow = (dm < nm) ? fminf(dm, nm4) : d4;
        } else {
            float e1 = 2.f / (float)p, e2 = 2.f * (float)p;
            tlow = (dm < nm) ? fminf(powf(dm, e1), powf(nm, e2)) : powf(dm, e2);
        }
        float alpha = -0.5f * __expf(-2.f * log_sigma[0]);
        nm2[mm]  = nm * nm;
        refs[mm] = alpha * tlow;   // alpha<0, t>=tlow => s<=ref (no overflow)
    }
}

// ---------------------------------------------------------------------------
// k_pass2: prologue loads nm2/ref for this block's 128 columns (1 KB).
// Main loop recomputes d^2 (D col = m orientation), sqrt-free hot path,
// accumulates sum_exp[m] += exp(alpha*t - ref).
// ---------------------------------------------------------------------------
__global__ __launch_bounds__(256) void k_pass2(const __hip_bfloat16* __restrict__ zf,
                                               const __hip_bfloat16* __restrict__ ebf,
                                               const float* __restrict__ zn2,
                                               const float* __restrict__ en2,
                                               const float* __restrict__ nm2,
                                               const float* __restrict__ refsg,
                                               const float* __restrict__ log_sigma,
                                               const int* __restrict__ pp,
                                               float* __restrict__ sume) {
    __shared__ float snm2[128], sref[128], ssum[128];
    int tid = threadIdx.x;
    int p = pp[0];
    float alpha = -0.5f * __expf(-2.f * log_sigma[0]);

    if (tid < 128) {
        int m = blockIdx.y * 128 + tid;
        snm2[tid] = nm2[m];
        sref[tid] = refsg[m];
        ssum[tid] = 0.f;
    }
    __syncthreads();

    int wave = tid >> 6, lane = tid & 63;
    int l16 = lane & 15, lq = lane >> 4;
    int wn = wave >> 1, wm = wave & 1;
    int n0 = blockIdx.x * 64 + wn * 32;
    int m0 = blockIdx.y * 128 + wm * 64;

    const bf16x8* zfv = reinterpret_cast<const bf16x8*>(zf);
    const bf16x8* ebv = reinterpret_cast<const bf16x8*>(ebf);

    bf16x8 Af[2][2], Bf[4][2];
#pragma unroll
    for (int i = 0; i < 2; i++)
#pragma unroll
        for (int h = 0; h < 2; h++)
            Af[i][h] = zfv[(size_t)(n0 + i * 16 + l16) * 8 + h * 4 + lq];
#pragma unroll
    for (int j = 0; j < 4; j++)
#pragma unroll
        for (int h = 0; h < 2; h++)
            Bf[j][h] = ebv[(size_t)(m0 + j * 16 + l16) * 8 + h * 4 + lq];

    f32x4 acc[2][4];
#pragma unroll
    for (int i = 0; i < 2; i++)
#pragma unroll
        for (int j = 0; j < 4; j++) {
            acc[i][j] = (f32x4){0.f, 0.f, 0.f, 0.f};
            acc[i][j] = __builtin_amdgcn_mfma_f32_16x16x32_bf16(Af[i][0], Bf[j][0], acc[i][j], 0, 0, 0);
            acc[i][j] = __builtin_amdgcn_mfma_f32_16x16x32_bf16(Af[i][1], Bf[j][1], acc[i][j], 0, 0, 0);
        }

    f32x4 zn2v[2];
#pragma unroll
    for (int i = 0; i < 2; i++)
        zn2v[i] = *reinterpret_cast<const f32x4*>(zn2 + n0 + i * 16 + lq * 4);

    bool p2 = (p == 2);
    float pe = (float)p, pi = 1.f / (float)p;

#pragma unroll
    for (int j = 0; j < 4; j++) {
        float en2v = en2[m0 + j * 16 + l16];
        float nm2v = snm2[wm * 64 + j * 16 + l16];
        float rfv  = sref[wm * 64 + j * 16 + l16];
        float csum = 0.f;
#pragma unroll
        for (int i = 0; i < 2; i++)
#pragma unroll
            for (int r = 0; r < 4; r++) {
                float d2c = fmaxf(zn2v[i][r] + en2v - 2.f * acc[i][j][r], 0.f);
                float t;
                if (p2) t = (d2c < nm2v) ? sqrtf(d2c) : d2c * d2c;   // d^1 / d^4
                else    t = powf(d2c, (d2c < nm2v) ? pi : pe);
                csum += __expf(fmaf(alpha, t, -rfv));
            }
        csum += __shfl_xor(csum, 16);
        csum += __shfl_xor(csum, 32);
        if (lane < 16) atomicAdd(&ssum[wm * 64 + j * 16 + lane], csum);
    }
    __syncthreads();
    if (tid < 128) atomicAdd(&sume[blockIdx.y * 128 + tid], ssum[tid]);
}

// ---------------------------------------------------------------------------
// k_final: loss = -mean(ref + log(sum_exp)) + z_dim * log_sigma
// ---------------------------------------------------------------------------
__global__ __launch_bounds__(256) void k_final(const float* __restrict__ refs,
                                               const float* __restrict__ sume,
                                               const float* __restrict__ log_sigma,
                                               float* __restrict__ out) {
    __shared__ float red[4];
    int tid = threadIdx.x;
    float a = 0.f;
    for (int m = tid; m < MM; m += 256)
        a += refs[m] + logf(fmaxf(sume[m], 1e-30f));
    for (int off = 32; off; off >>= 1) a += __shfl_xor(a, off);
    int wave = tid >> 6, lane = tid & 63;
    if (lane == 0) red[wave] = a;
    __syncthreads();
    if (tid == 0) {
        float t = red[0] + red[1] + red[2] + red[3];
        out[0] = -t / (float)MM + (float)ZD * log_sigma[0];
    }
}

// ---------------------------------------------------------------------------
extern "C" void kernel_launch(void* const* d_in, const int* in_sizes, int n_in,
                              void* d_out, int out_size, void* d_ws, size_t ws_size,
                              hipStream_t stream) {
    const float* z            = (const float*)d_in[0];
    const float* e            = (const float*)d_in[1];
    const float* belong       = (const float*)d_in[2];
    const float* log_sigma    = (const float*)d_in[3];
    const float* max_distance = (const float*)d_in[4];
    const int*   pp           = (const int*)d_in[5];
    float* out = (float*)d_out;

    char* ws = (char*)d_ws;
    __hip_bfloat16* zf  = (__hip_bfloat16*)(ws + 0);        // 2,097,152 B
    __hip_bfloat16* ebf = (__hip_bfloat16*)(ws + 2097152);  //   524,288 B
    float* zn2  = (float*)(ws + 2621440);                   //    65,536 B
    float* en2  = (float*)(ws + 2686976);                   //    16,384 B
    float* pmax = (float*)(ws + 2703360);                   // 2,097,152 B
    float* pmin = (float*)(ws + 4800512);                   // 2,097,152 B
    float* nm2  = (float*)(ws + 6897664);                   //    16,384 B
    float* refs = (float*)(ws + 6914048);                   //    16,384 B
    float* sume = (float*)(ws + 6930432);                   //    16,384 B

    k_prep<<<1280, 256, 0, stream>>>(z, e, zf, ebf, zn2, en2, sume);
    k_pass1<<<dim3(MM / 64, NN / 128), 256, 0, stream>>>(zf, ebf, zn2, en2, belong, pmax, pmin);
    k_mid<<<MM / 64, 256, 0, stream>>>(pmax, pmin, max_distance, log_sigma, pp, nm2, refs);
    k_pass2<<<dim3(NN / 64, MM / 128), 256, 0, stream>>>(zf, ebf, zn2, en2, nm2, refs,
                                                         log_sigma, pp, sume);
    k_final<<<1, 256, 0, stream>>>(refs, sume, log_sigma, out);
}